// Round 1
// baseline (323.874 us; speedup 1.0000x reference)
//
#include <hip/hip_runtime.h>
#include <hip/hip_bf16.h>
#include <math.h>

#define BDIM 4096
#define DDIM 256
#define N2   8192
#define BM   32
#define BN   128
#define LDK  264   // padded LDS K-stride (elements): 264*2B=528B row stride -> 2-way bank aliasing (free)

typedef __bf16 bf16x8 __attribute__((ext_vector_type(8)));
typedef __bf16 bf16x4 __attribute__((ext_vector_type(4)));
typedef float  f32x4  __attribute__((ext_vector_type(4)));

// ---------------- Kernel 1: L2-normalize rows, emit bf16 reps + fp32 positive dots ----------------
__global__ __launch_bounds__(256) void norm_kernel(const float* __restrict__ z1,
                                                   const float* __restrict__ z2,
                                                   __bf16* __restrict__ reps,
                                                   float* __restrict__ pos) {
    int gwave = (blockIdx.x * 256 + threadIdx.x) >> 6;   // one wave per row i
    int lane  = threadIdx.x & 63;
    if (gwave >= BDIM) return;

    const float4 a = *(const float4*)&z1[(size_t)gwave * DDIM + lane * 4];
    const float4 b = *(const float4*)&z2[(size_t)gwave * DDIM + lane * 4];

    float s1 = a.x*a.x + a.y*a.y + a.z*a.z + a.w*a.w;
    float s2 = b.x*b.x + b.y*b.y + b.z*b.z + b.w*b.w;
    float d  = a.x*b.x + a.y*b.y + a.z*b.z + a.w*b.w;
    #pragma unroll
    for (int off = 32; off; off >>= 1) {
        s1 += __shfl_xor(s1, off);
        s2 += __shfl_xor(s2, off);
        d  += __shfl_xor(d,  off);
    }
    float r1 = 1.0f / fmaxf(sqrtf(s1), 1e-12f);
    float r2 = 1.0f / fmaxf(sqrtf(s2), 1e-12f);

    bf16x4 w1, w2;
    w1[0] = (__bf16)(a.x * r1); w1[1] = (__bf16)(a.y * r1);
    w1[2] = (__bf16)(a.z * r1); w1[3] = (__bf16)(a.w * r1);
    w2[0] = (__bf16)(b.x * r2); w2[1] = (__bf16)(b.y * r2);
    w2[2] = (__bf16)(b.z * r2); w2[3] = (__bf16)(b.w * r2);
    *(bf16x4*)&reps[(size_t)gwave * DDIM + lane * 4]          = w1;
    *(bf16x4*)&reps[(size_t)(gwave + BDIM) * DDIM + lane * 4] = w2;

    if (lane == 0) pos[gwave] = d * r1 * r2;   // cosine of the positive pair (fp32)
}

// ---------------- Kernel 2: fused GEMM (reps @ reps^T) + exp-sum per row ----------------
// Grid: N2/BM = 256 blocks, 256 threads = 4 waves in a 2x2 wave grid.
// Each block owns rows [r0, r0+32); loops over all 8192 cols in tiles of 128.
__global__ __launch_bounds__(256) void lse_kernel(const __bf16* __restrict__ reps,
                                                  float* __restrict__ rowlog) {
    __shared__ __bf16 At[BM * LDK];
    __shared__ __bf16 Bt[BN * LDK];
    __shared__ float  rowacc[2][BM];

    const int tid  = threadIdx.x;
    const int wave = tid >> 6;
    const int lane = tid & 63;
    const int r0   = blockIdx.x * BM;
    const int wr   = wave >> 1;          // row-half of wave (0/1): rows wr*16..
    const int wc   = wave & 1;           // col-half of wave (0/1): cols wc*64..

    // stage A tile (32 rows x 256 k), 16B chunks
    for (int c = tid; c < BM * 32; c += 256) {
        int row = c >> 5, cc = c & 31;
        *(uint4*)&At[row * LDK + cc * 8] =
            *(const uint4*)&reps[(size_t)(r0 + row) * DDIM + cc * 8];
    }
    __syncthreads();

    // hoist this wave's A fragments (16 rows x 256 k) into registers
    const int l15 = lane & 15;
    const int lq  = lane >> 4;           // quarter-wave index 0..3
    const int akb = lq * 8;
    bf16x8 afr[8];
    #pragma unroll
    for (int ks = 0; ks < 8; ++ks)
        afr[ks] = *(const bf16x8*)&At[(wr * 16 + l15) * LDK + ks * 32 + akb];

    float S[4] = {0.f, 0.f, 0.f, 0.f};
    const int grow     = r0 + wr * 16 + lq * 4;  // + reg -> global row of acc element
    const int gcolbase = wc * 64 + l15;          // + ct + fn*16 -> global col

    for (int ct = 0; ct < N2; ct += BN) {
        __syncthreads();   // previous tile's ds_reads done before overwrite
        for (int c = tid; c < BN * 32; c += 256) {
            int row = c >> 5, cc = c & 31;
            *(uint4*)&Bt[row * LDK + cc * 8] =
                *(const uint4*)&reps[(size_t)(ct + row) * DDIM + cc * 8];
        }
        __syncthreads();

        f32x4 acc[4];
        #pragma unroll
        for (int fn = 0; fn < 4; ++fn)
            #pragma unroll
            for (int q = 0; q < 4; ++q) acc[fn][q] = 0.f;

        #pragma unroll
        for (int ks = 0; ks < 8; ++ks) {
            #pragma unroll
            for (int fn = 0; fn < 4; ++fn) {
                bf16x8 bfr = *(const bf16x8*)&Bt[(wc * 64 + fn * 16 + l15) * LDK + ks * 32 + akb];
                acc[fn] = __builtin_amdgcn_mfma_f32_16x16x32_bf16(afr[ks], bfr, acc[fn], 0, 0, 0);
            }
        }

        // epilogue: S[r] += exp(2*sim - 2), skipping the diagonal element
        #pragma unroll
        for (int fn = 0; fn < 4; ++fn) {
            int gcol = ct + gcolbase + fn * 16;
            #pragma unroll
            for (int r = 0; r < 4; ++r) {
                float e = __expf(2.0f * acc[fn][r] - 2.0f);
                S[r] += (gcol == grow + r) ? 0.0f : e;
            }
        }
    }

    // reduce the 16 column-lanes of each quarter-wave
    #pragma unroll
    for (int off = 1; off < 16; off <<= 1)
        #pragma unroll
        for (int r = 0; r < 4; ++r) S[r] += __shfl_xor(S[r], off);

    if (l15 == 0) {
        #pragma unroll
        for (int r = 0; r < 4; ++r)
            rowacc[wc][wr * 16 + lq * 4 + r] = S[r];
    }
    __syncthreads();
    if (tid < BM)
        rowlog[r0 + tid] = logf(rowacc[0][tid] + rowacc[1][tid]);
}

// ---------------- Kernel 3: final scalar reduction ----------------
__global__ __launch_bounds__(256) void finish_kernel(const float* __restrict__ rowlog,
                                                     const float* __restrict__ pos,
                                                     float* __restrict__ out) {
    float v = 0.f;
    for (int i = threadIdx.x; i < N2; i += 256)   v += rowlog[i];
    float p = 0.f;
    for (int i = threadIdx.x; i < BDIM; i += 256) p += pos[i];
    v -= 4.0f * p;
    #pragma unroll
    for (int off = 32; off; off >>= 1) v += __shfl_xor(v, off);
    __shared__ float wsum[4];
    if ((threadIdx.x & 63) == 0) wsum[threadIdx.x >> 6] = v;
    __syncthreads();
    if (threadIdx.x == 0)
        out[0] = 2.0f + (wsum[0] + wsum[1] + wsum[2] + wsum[3]) / (float)N2;
}

extern "C" void kernel_launch(void* const* d_in, const int* in_sizes, int n_in,
                              void* d_out, int out_size, void* d_ws, size_t ws_size,
                              hipStream_t stream) {
    const float* z1 = (const float*)d_in[0];
    const float* z2 = (const float*)d_in[1];
    float* out = (float*)d_out;

    __bf16* reps  = (__bf16*)d_ws;                                   // 8192*256*2B = 4 MB
    float* rowlog = (float*)((char*)d_ws + (size_t)N2 * DDIM * 2);   // 32 KB
    float* pos    = rowlog + N2;                                     // 16 KB

    norm_kernel<<<BDIM / 4, 256, 0, stream>>>(z1, z2, reps, pos);
    lse_kernel<<<N2 / BM, 256, 0, stream>>>(reps, rowlog);
    finish_kernel<<<1, 256, 0, stream>>>(rowlog, pos, out);
}

// Round 2
// 137.838 us; speedup vs baseline: 2.3497x; 2.3497x over previous
//
#include <hip/hip_runtime.h>
#include <hip/hip_bf16.h>
#include <math.h>

#define BDIM 4096
#define DDIM 256
#define N2   8192
#define CSPLIT 16
#define MROWS 32
#define CPW (N2 / CSPLIT)   // 512 cols per wave

typedef __bf16 bf16x8 __attribute__((ext_vector_type(8)));
typedef __bf16 bf16x4 __attribute__((ext_vector_type(4)));
typedef float  f32x4  __attribute__((ext_vector_type(4)));

// ---------------- Kernel 1: L2-normalize rows, emit bf16 reps + fp32 positive dots ----------------
__global__ __launch_bounds__(256) void norm_kernel(const float* __restrict__ z1,
                                                   const float* __restrict__ z2,
                                                   __bf16* __restrict__ reps,
                                                   float* __restrict__ pos) {
    int gwave = (blockIdx.x * 256 + threadIdx.x) >> 6;   // one wave per row i
    int lane  = threadIdx.x & 63;
    if (gwave >= BDIM) return;

    const float4 a = *(const float4*)&z1[(size_t)gwave * DDIM + lane * 4];
    const float4 b = *(const float4*)&z2[(size_t)gwave * DDIM + lane * 4];

    float s1 = a.x*a.x + a.y*a.y + a.z*a.z + a.w*a.w;
    float s2 = b.x*b.x + b.y*b.y + b.z*b.z + b.w*b.w;
    float d  = a.x*b.x + a.y*b.y + a.z*b.z + a.w*b.w;
    #pragma unroll
    for (int off = 32; off; off >>= 1) {
        s1 += __shfl_xor(s1, off);
        s2 += __shfl_xor(s2, off);
        d  += __shfl_xor(d,  off);
    }
    float r1 = 1.0f / fmaxf(sqrtf(s1), 1e-12f);
    float r2 = 1.0f / fmaxf(sqrtf(s2), 1e-12f);

    bf16x4 w1, w2;
    w1[0] = (__bf16)(a.x * r1); w1[1] = (__bf16)(a.y * r1);
    w1[2] = (__bf16)(a.z * r1); w1[3] = (__bf16)(a.w * r1);
    w2[0] = (__bf16)(b.x * r2); w2[1] = (__bf16)(b.y * r2);
    w2[2] = (__bf16)(b.z * r2); w2[3] = (__bf16)(b.w * r2);
    *(bf16x4*)&reps[(size_t)gwave * DDIM + lane * 4]          = w1;
    *(bf16x4*)&reps[(size_t)(gwave + BDIM) * DDIM + lane * 4] = w2;

    if (lane == 0) pos[gwave] = d * r1 * r2;
}

// ---------------- Kernel 2: barrier-free streaming GEMM + exp-sum ----------------
// 4096 independent waves: wave (rg, cs) computes rows [rg*32, rg*32+32) x cols
// [cs*512, cs*512+512). A-frags (32 rows x K=256) live in 64 VGPRs for the whole
// kernel; B-frags stream from global (reps is 4MB -> resident in every XCD L2).
// No LDS, no __syncthreads, no bank conflicts.
__global__ __launch_bounds__(256) void lse2_kernel(const __bf16* __restrict__ reps,
                                                   float* __restrict__ partial) {
    const int tid  = threadIdx.x;
    const int w    = blockIdx.x * 4 + (tid >> 6);
    const int lane = tid & 63;
    const int l15  = lane & 15;
    const int lq   = lane >> 4;
    const int rg   = w >> 4;            // 0..255 row-group
    const int cs   = w & (CSPLIT - 1);  // 0..15 column slice
    const int r0   = rg * MROWS;
    const int cbase = cs * CPW;

    // hoist A fragments: rows r0..r0+31, all K=256
    const bf16x8* a0p = (const bf16x8*)(reps + (size_t)(r0 + l15) * DDIM + lq * 8);
    const bf16x8* a1p = (const bf16x8*)(reps + (size_t)(r0 + 16 + l15) * DDIM + lq * 8);
    bf16x8 afr0[8], afr1[8];
    #pragma unroll
    for (int ks = 0; ks < 8; ++ks) { afr0[ks] = a0p[ks * 4]; afr1[ks] = a1p[ks * 4]; }

    const bf16x8* bp = (const bf16x8*)(reps + (size_t)(cbase + l15) * DDIM + lq * 8);
    // column-group stride in bf16x8 units: 16 rows * 256 elems / 8 = 512

    f32x4 S0 = {0.f, 0.f, 0.f, 0.f}, S1 = {0.f, 0.f, 0.f, 0.f};
    const int rowa = r0 + lq * 4;

    bf16x8 b0[8], b1[8];
    #pragma unroll
    for (int ks = 0; ks < 8; ++ks) b0[ks] = bp[ks * 4];

    #pragma unroll 1
    for (int fg = 0; fg < 32; fg += 2) {
        // prefetch fg+1 while computing fg
        #pragma unroll
        for (int ks = 0; ks < 8; ++ks) b1[ks] = bp[(fg + 1) * 512 + ks * 4];
        {
            f32x4 acc0 = {0.f,0.f,0.f,0.f}, acc1 = {0.f,0.f,0.f,0.f};
            #pragma unroll
            for (int ks = 0; ks < 8; ++ks) {
                acc0 = __builtin_amdgcn_mfma_f32_16x16x32_bf16(afr0[ks], b0[ks], acc0, 0, 0, 0);
                acc1 = __builtin_amdgcn_mfma_f32_16x16x32_bf16(afr1[ks], b0[ks], acc1, 0, 0, 0);
            }
            const int col = cbase + fg * 16 + l15;
            #pragma unroll
            for (int r = 0; r < 4; ++r) {
                float e0 = __expf(2.0f * acc0[r] - 2.0f);
                float e1 = __expf(2.0f * acc1[r] - 2.0f);
                S0[r] += (col == rowa + r)      ? 0.0f : e0;
                S1[r] += (col == rowa + 16 + r) ? 0.0f : e1;
            }
        }
        // prefetch fg+2 while computing fg+1
        if (fg + 2 < 32) {
            #pragma unroll
            for (int ks = 0; ks < 8; ++ks) b0[ks] = bp[(fg + 2) * 512 + ks * 4];
        }
        {
            f32x4 acc0 = {0.f,0.f,0.f,0.f}, acc1 = {0.f,0.f,0.f,0.f};
            #pragma unroll
            for (int ks = 0; ks < 8; ++ks) {
                acc0 = __builtin_amdgcn_mfma_f32_16x16x32_bf16(afr0[ks], b1[ks], acc0, 0, 0, 0);
                acc1 = __builtin_amdgcn_mfma_f32_16x16x32_bf16(afr1[ks], b1[ks], acc1, 0, 0, 0);
            }
            const int col = cbase + (fg + 1) * 16 + l15;
            #pragma unroll
            for (int r = 0; r < 4; ++r) {
                float e0 = __expf(2.0f * acc0[r] - 2.0f);
                float e1 = __expf(2.0f * acc1[r] - 2.0f);
                S0[r] += (col == rowa + r)      ? 0.0f : e0;
                S1[r] += (col == rowa + 16 + r) ? 0.0f : e1;
            }
        }
    }

    // reduce over the 16 column-lanes (xor bits 0..3 stay within the lq group)
    #pragma unroll
    for (int off = 1; off < 16; off <<= 1) {
        #pragma unroll
        for (int r = 0; r < 4; ++r) {
            S0[r] += __shfl_xor(S0[r], off);
            S1[r] += __shfl_xor(S1[r], off);
        }
    }
    if (l15 == 0) {
        #pragma unroll
        for (int r = 0; r < 4; ++r) {
            partial[(size_t)cs * N2 + r0 + lq * 4 + r]      = S0[r];
            partial[(size_t)cs * N2 + r0 + 16 + lq * 4 + r] = S1[r];
        }
    }
}

// ---------------- Kernel 3a: per-row log of summed partials, per-block sums ----------------
__global__ __launch_bounds__(256) void finish1_kernel(const float* __restrict__ partial,
                                                      float* __restrict__ blocksum) {
    int row = blockIdx.x * 256 + threadIdx.x;
    float s = 0.f;
    #pragma unroll
    for (int cs = 0; cs < CSPLIT; ++cs) s += partial[(size_t)cs * N2 + row];
    float v = logf(s);
    #pragma unroll
    for (int off = 32; off; off >>= 1) v += __shfl_xor(v, off);
    __shared__ float ws4[4];
    if ((threadIdx.x & 63) == 0) ws4[threadIdx.x >> 6] = v;
    __syncthreads();
    if (threadIdx.x == 0) blocksum[blockIdx.x] = ws4[0] + ws4[1] + ws4[2] + ws4[3];
}

// ---------------- Kernel 3b: final scalar ----------------
__global__ __launch_bounds__(256) void finish2_kernel(const float* __restrict__ blocksum,
                                                      const float* __restrict__ pos,
                                                      float* __restrict__ out) {
    float v = (threadIdx.x < 32) ? blocksum[threadIdx.x] : 0.f;
    float p = 0.f;
    for (int i = threadIdx.x; i < BDIM; i += 256) p += pos[i];
    float t = v - 4.0f * p;
    #pragma unroll
    for (int off = 32; off; off >>= 1) t += __shfl_xor(t, off);
    __shared__ float ws4[4];
    if ((threadIdx.x & 63) == 0) ws4[threadIdx.x >> 6] = t;
    __syncthreads();
    if (threadIdx.x == 0)
        out[0] = 2.0f + (ws4[0] + ws4[1] + ws4[2] + ws4[3]) / (float)N2;
}

extern "C" void kernel_launch(void* const* d_in, const int* in_sizes, int n_in,
                              void* d_out, int out_size, void* d_ws, size_t ws_size,
                              hipStream_t stream) {
    const float* z1 = (const float*)d_in[0];
    const float* z2 = (const float*)d_in[1];
    float* out = (float*)d_out;

    __bf16* reps    = (__bf16*)d_ws;                                    // 4 MB
    float*  partial = (float*)((char*)d_ws + (size_t)N2 * DDIM * 2);    // 16*8192*4 = 512 KB
    float*  pos     = partial + (size_t)CSPLIT * N2;                    // 16 KB
    float*  blocksum = pos + BDIM;                                      // 128 B

    norm_kernel<<<BDIM / 4, 256, 0, stream>>>(z1, z2, reps, pos);
    lse2_kernel<<<(256 * CSPLIT) / 4, 256, 0, stream>>>(reps, partial);
    finish1_kernel<<<N2 / 256, 256, 0, stream>>>(partial, blocksum);
    finish2_kernel<<<1, 256, 0, stream>>>(blocksum, pos, out);
}

// Round 3
// 58.994 us; speedup vs baseline: 5.4899x; 2.3365x over previous
//
#include <hip/hip_runtime.h>
#include <hip/hip_bf16.h>
#include <math.h>

#define BDIM 4096
#define DDIM 256
#define N2   8192
#define CSPLIT 16
#define BROWS 256            // rows per block (4 waves x 64 rows)
#define CPB (N2 / CSPLIT)    // 512 cols per block
#define BN 64                // col tile (32 KB LDS per buffer)
#define NT (CPB / BN)        // 8 tiles per block

typedef __bf16 bf16x8 __attribute__((ext_vector_type(8)));
typedef __bf16 bf16x4 __attribute__((ext_vector_type(4)));
typedef float  f32x4  __attribute__((ext_vector_type(4)));

__device__ __forceinline__ void gload_lds16(const __bf16* g, void* lds) {
    __builtin_amdgcn_global_load_lds(
        (const __attribute__((address_space(1))) unsigned int*)g,
        (__attribute__((address_space(3))) unsigned int*)lds, 16, 0, 0);
}

// ---------------- Kernel 1: L2-normalize rows, emit bf16 reps + fp32 positive dots ----------------
__global__ __launch_bounds__(256) void norm_kernel(const float* __restrict__ z1,
                                                   const float* __restrict__ z2,
                                                   __bf16* __restrict__ reps,
                                                   float* __restrict__ pos) {
    int gwave = (blockIdx.x * 256 + threadIdx.x) >> 6;
    int lane  = threadIdx.x & 63;
    if (gwave >= BDIM) return;

    const float4 a = *(const float4*)&z1[(size_t)gwave * DDIM + lane * 4];
    const float4 b = *(const float4*)&z2[(size_t)gwave * DDIM + lane * 4];

    float s1 = a.x*a.x + a.y*a.y + a.z*a.z + a.w*a.w;
    float s2 = b.x*b.x + b.y*b.y + b.z*b.z + b.w*b.w;
    float d  = a.x*b.x + a.y*b.y + a.z*b.z + a.w*b.w;
    #pragma unroll
    for (int off = 32; off; off >>= 1) {
        s1 += __shfl_xor(s1, off);
        s2 += __shfl_xor(s2, off);
        d  += __shfl_xor(d,  off);
    }
    float r1 = 1.0f / fmaxf(sqrtf(s1), 1e-12f);
    float r2 = 1.0f / fmaxf(sqrtf(s2), 1e-12f);

    bf16x4 w1, w2;
    w1[0] = (__bf16)(a.x * r1); w1[1] = (__bf16)(a.y * r1);
    w1[2] = (__bf16)(a.z * r1); w1[3] = (__bf16)(a.w * r1);
    w2[0] = (__bf16)(b.x * r2); w2[1] = (__bf16)(b.y * r2);
    w2[2] = (__bf16)(b.z * r2); w2[3] = (__bf16)(b.w * r2);
    *(bf16x4*)&reps[(size_t)gwave * DDIM + lane * 4]          = w1;
    *(bf16x4*)&reps[(size_t)(gwave + BDIM) * DDIM + lane * 4] = w2;

    if (lane == 0) pos[gwave] = d * r1 * r2;
}

// ---------------- Kernel 2: LDS-tiled GEMM (reps @ reps^T) + exp-sum ----------------
// Grid: 32 row-groups x 16 col-slices = 512 blocks (2/CU). Block = 4 waves.
// Each wave holds A for 64 rows x K=256 in registers (128 VGPR). B tiles
// (64 cols x 256 k = 32 KB) stream through double-buffered LDS via
// global_load_lds(16B), with XOR-swizzled source addresses so the MFMA
// ds_read_b128 pattern is bank-conflict-free (chunk ^= row&7).
__global__ __launch_bounds__(256, 2) void lse3_kernel(const __bf16* __restrict__ reps,
                                                      float* __restrict__ partial) {
    __shared__ __attribute__((aligned(16))) __bf16 Bt[2][BN * DDIM];  // 2 x 32 KB

    const int tid  = threadIdx.x;
    const int wave = tid >> 6;
    const int lane = tid & 63;
    const int l15  = lane & 15;
    const int lq   = lane >> 4;
    const int rg   = blockIdx.x >> 4;       // 0..31
    const int cs   = blockIdx.x & 15;       // 0..15
    const int r0   = rg * BROWS;
    const int c0   = cs * CPB;

    // hoist A fragments: 4 groups of 16 rows, full K=256
    bf16x8 afr[4][8];
    #pragma unroll
    for (int g = 0; g < 4; ++g) {
        const __bf16* ap = reps + (size_t)(r0 + wave * 64 + g * 16 + l15) * DDIM + lq * 8;
        #pragma unroll
        for (int ks = 0; ks < 8; ++ks)
            afr[g][ks] = *(const bf16x8*)(ap + ks * 32);
    }

    f32x4 S[4];
    #pragma unroll
    for (int g = 0; g < 4; ++g)
        #pragma unroll
        for (int r = 0; r < 4; ++r) S[g][r] = 0.f;

    // stage tile t into buffer `buf`: linear LDS dest, XOR-swizzled global source
    auto stage = [&](int buf, int t) {
        const size_t gcol = (size_t)(c0 + t * BN);
        #pragma unroll
        for (int i = 0; i < 8; ++i) {
            int L  = wave * 8192 + i * 1024 + lane * 16;   // byte offset in tile
            int c  = L >> 9;                               // tile col (row of B-slab)
            int ch = (L >> 4) & 31;                        // 16B chunk within row
            const __bf16* g = reps + (gcol + c) * DDIM + (size_t)((ch ^ (c & 7)) << 3);
            gload_lds16(g, (char*)&Bt[buf][0] + (wave * 8192 + i * 1024));
        }
    };

    stage(0, 0);
    __syncthreads();   // drains vmcnt(0): tile 0 resident

    #pragma unroll 1
    for (int t = 0; t < NT; ++t) {
        const int cur = t & 1;
        if (t + 1 < NT) stage(cur ^ 1, t + 1);   // issue next-tile loads first

        const char* bufc = (const char*)&Bt[cur][0];
        #pragma unroll
        for (int fg = 0; fg < 4; ++fg) {
            const int c = fg * 16 + l15;
            const char* rowp = bufc + c * 512;
            const int cx = c & 7;
            bf16x8 bf[8];
            #pragma unroll
            for (int ks = 0; ks < 8; ++ks)
                bf[ks] = *(const bf16x8*)(rowp + (((ks * 4 + lq) ^ cx) << 4));

            f32x4 acc[4] = {{0.f,0.f,0.f,0.f},{0.f,0.f,0.f,0.f},
                            {0.f,0.f,0.f,0.f},{0.f,0.f,0.f,0.f}};
            #pragma unroll
            for (int ks = 0; ks < 8; ++ks)
                #pragma unroll
                for (int g = 0; g < 4; ++g)
                    acc[g] = __builtin_amdgcn_mfma_f32_16x16x32_bf16(afr[g][ks], bf[ks], acc[g], 0, 0, 0);

            #pragma unroll
            for (int g = 0; g < 4; ++g)
                #pragma unroll
                for (int r = 0; r < 4; ++r)
                    S[g][r] += __expf(2.0f * acc[g][r] - 2.0f);
        }
        __syncthreads();   // vmcnt(0) + lgkmcnt(0) + barrier: next tile ready, cur free
    }

    // reduce across the 16 column-lanes
    #pragma unroll
    for (int off = 1; off < 16; off <<= 1)
        #pragma unroll
        for (int g = 0; g < 4; ++g)
            #pragma unroll
            for (int r = 0; r < 4; ++r) S[g][r] += __shfl_xor(S[g][r], off);

    if (l15 == 0) {
        #pragma unroll
        for (int g = 0; g < 4; ++g)
            #pragma unroll
            for (int r = 0; r < 4; ++r) {
                int row = r0 + wave * 64 + g * 16 + lq * 4 + r;
                float v = S[g][r];
                // diagonal col is in this slice: its exp(2*||r||^2-2) ~= 1.0
                if (row >= c0 && row < c0 + CPB) v -= 1.0f;
                partial[(size_t)cs * N2 + row] = v;
            }
    }
}

// ---------------- Kernel 3a: per-row log of summed partials, per-block sums ----------------
__global__ __launch_bounds__(256) void finish1_kernel(const float* __restrict__ partial,
                                                      float* __restrict__ blocksum) {
    int row = blockIdx.x * 256 + threadIdx.x;
    float s = 0.f;
    #pragma unroll
    for (int cs = 0; cs < CSPLIT; ++cs) s += partial[(size_t)cs * N2 + row];
    float v = logf(s);
    #pragma unroll
    for (int off = 32; off; off >>= 1) v += __shfl_xor(v, off);
    __shared__ float ws4[4];
    if ((threadIdx.x & 63) == 0) ws4[threadIdx.x >> 6] = v;
    __syncthreads();
    if (threadIdx.x == 0) blocksum[blockIdx.x] = ws4[0] + ws4[1] + ws4[2] + ws4[3];
}

// ---------------- Kernel 3b: final scalar ----------------
__global__ __launch_bounds__(256) void finish2_kernel(const float* __restrict__ blocksum,
                                                      const float* __restrict__ pos,
                                                      float* __restrict__ out) {
    float v = (threadIdx.x < 32) ? blocksum[threadIdx.x] : 0.f;
    float p = 0.f;
    for (int i = threadIdx.x; i < BDIM; i += 256) p += pos[i];
    float t = v - 4.0f * p;
    #pragma unroll
    for (int off = 32; off; off >>= 1) t += __shfl_xor(t, off);
    __shared__ float ws4[4];
    if ((threadIdx.x & 63) == 0) ws4[threadIdx.x >> 6] = t;
    __syncthreads();
    if (threadIdx.x == 0)
        out[0] = 2.0f + (ws4[0] + ws4[1] + ws4[2] + ws4[3]) / (float)N2;
}

extern "C" void kernel_launch(void* const* d_in, const int* in_sizes, int n_in,
                              void* d_out, int out_size, void* d_ws, size_t ws_size,
                              hipStream_t stream) {
    const float* z1 = (const float*)d_in[0];
    const float* z2 = (const float*)d_in[1];
    float* out = (float*)d_out;

    __bf16* reps     = (__bf16*)d_ws;                                  // 4 MB
    float*  partial  = (float*)((char*)d_ws + (size_t)N2 * DDIM * 2);  // 512 KB
    float*  pos      = partial + (size_t)CSPLIT * N2;                  // 16 KB
    float*  blocksum = pos + BDIM;                                     // 128 B

    norm_kernel<<<BDIM / 4, 256, 0, stream>>>(z1, z2, reps, pos);
    lse3_kernel<<<(N2 / BROWS) * CSPLIT, 256, 0, stream>>>(reps, partial);
    finish1_kernel<<<N2 / 256, 256, 0, stream>>>(partial, blocksum);
    finish2_kernel<<<1, 256, 0, stream>>>(blocksum, pos, out);
}